// Round 4
// baseline (228.055 us; speedup 1.0000x reference)
//
#include <hip/hip_runtime.h>

// AdaptiveAttention: softmax is shift-invariant along the reduced axis, so
// out = softmax(alpha * QK^T) @ V. Two kernels:
//  1) prepass: K -> fp16, V -> transposed bf16 (LDS-mediated transpose so both
//     global sides are coalesced), into d_ws as per-(head,kt) 32KB blocks with
//     XOR-swizzled 16B granules (conflict-free MFMA LDS reads).
//  2) attention: 64 QUERIES PER WAVE (4 query-halves of 16), 2 waves per
//     block, BQ=128, 512 blocks. The LDS data path is the dominant pipe
//     (~63% at 32q/wave): each wave reads the whole 32KB K+V tile through
//     LDS regardless of MFMA count, so the only lever on LDS-bytes-per-FLOP
//     is queries/wave. At 64q/wave every K/V fragment read feeds 4 MFMAs
//     (was 2) -> LDS traffic per FLOP halves. Double-buffered
//     global_load_lds staging, single-pass fp16 QK^T, unnormalized exp2
//     softmax (logits bounded; /l at the end), bf16 PV (unnormalized p
//     reaches ~2^40: overflows fp16, not bf16).
//     QK^T is mt-outer / half-inner so st transients stay at 16 VGPRs
//     (persistent: qf 64 + o 128).
// ws requirement: 32 heads * 32 ktiles * 32KB = 32 MB.

#define S_LEN 2048
#define HD    128
#define BQ    128
#define BK    64
#define NW    2
#define NH    4              // query-halves (16 q each) per wave
#define NT    (S_LEN / BK)   // 32 k-tiles
#define TILE_USH 16384       // 32KB per (head,kt): K 8192 | Vt 8192 ushorts

typedef __bf16    bf16x8 __attribute__((ext_vector_type(8)));
typedef __bf16    bf16x4 __attribute__((ext_vector_type(4)));
typedef _Float16  f16x8  __attribute__((ext_vector_type(8)));
typedef float     f32x4  __attribute__((ext_vector_type(4)));

__device__ __forceinline__ unsigned short f2bf(float x) {
  unsigned u = __builtin_bit_cast(unsigned, x);
  u = (u + 0x7FFFu + ((u >> 16) & 1u)) >> 16;   // RNE
  return (unsigned short)u;
}
__device__ __forceinline__ unsigned short f2h(float x) {
  _Float16 h = (_Float16)x;                      // v_cvt_f16_f32, RNE
  return __builtin_bit_cast(unsigned short, h);
}
__device__ __forceinline__ float fast_exp2(float x) {
#if __has_builtin(__builtin_amdgcn_exp2f)
  return __builtin_amdgcn_exp2f(x);
#else
  return exp2f(x);
#endif
}

// ---------- prepass: convert + transpose + swizzle into ws ----------
__global__ __launch_bounds__(256) void attn_prepass_kernel(
    const float* __restrict__ kg, const float* __restrict__ vg,
    unsigned short* __restrict__ ws) {
  __shared__ float T[64 * 130];         // V staging, stride 130 (b64-aligned)
  const int blk  = blockIdx.x;          // head*32 + kt
  const int head = blk >> 5;
  const int kt   = blk & 31;
  const int tid  = threadIdx.x;
  const size_t hoff = (size_t)head * S_LEN * HD;
  const float* kp = kg + hoff + (size_t)kt * BK * HD;
  const float* vp = vg + hoff + (size_t)kt * BK * HD;
  unsigned short* wsK  = ws + (size_t)blk * TILE_USH;
  unsigned short* wsVt = wsK + 8192;

  // K (fp16): granule (key, ch) = dims [ch*8, ch*8+8) of row key.
  // slot = (ch&8) | ((ch&7) ^ (key&7))  -> conflict-free b128 fragment reads.
#pragma unroll
  for (int it = 0; it < 4; ++it) {
    int idx = it * 256 + tid;           // 0..1023
    int key = idx >> 4;
    int ch  = idx & 15;
    const float* src = kp + key * HD + ch * 8;
    float4 a = *(const float4*)src;
    float4 b = *(const float4*)(src + 4);
    float xs[8] = {a.x, a.y, a.z, a.w, b.x, b.y, b.z, b.w};
    union { unsigned short s[8]; uint4 v; } hi;
#pragma unroll
    for (int j = 0; j < 8; ++j) hi.s[j] = f2h(xs[j]);
    int slot = (ch & 8) | ((ch & 7) ^ (key & 7));
    *(uint4*)&wsK[key * 128 + slot * 8] = hi.v;
  }

  // V^T via LDS: phase 1 -- coalesced float2 loads, contiguous LDS rows.
#pragma unroll
  for (int it = 0; it < 16; ++it) {
    int idx = it * 256 + tid;           // 0..4095 float2 granules
    int key = idx >> 6;                 // 64 float2 per row
    int c2  = idx & 63;
    float2 a = *(const float2*)(vp + (size_t)key * HD + c2 * 2);
    *(float2*)&T[key * 130 + c2 * 2] = a;
  }
  __syncthreads();

  // phase 2 -- column gather from LDS (<=4-way conflicts), coalesced granule
  // writes. granule (dim, ch) = keys [ch*8, ch*8+8) of column dim;
  // slot = ch ^ (dim&7).
#pragma unroll
  for (int r = 0; r < 4; ++r) {
    int idx = r * 256 + tid;            // 0..1023
    int dim = idx >> 3;                 // 0..127
    int ch  = idx & 7;
    union { unsigned short s[8]; uint4 v; } gg;
#pragma unroll
    for (int j = 0; j < 8; ++j) gg.s[j] = f2bf(T[(ch * 8 + j) * 130 + dim]);
    int slot = ch ^ (dim & 7);
    *(uint4*)&wsVt[dim * 64 + slot * 8] = gg.v;
  }
}

// ---------- attention ----------
__device__ __forceinline__ void stage_tile(const unsigned short* __restrict__ wt,
                                           unsigned short* dst, int tid, int w) {
  // 16 rounds x 128 lanes x 16B = 32KB. LDS dest is wave-uniform base (w*64
  // granules) + implicit lane*16B -- the m104/m108 requirement.
#pragma unroll
  for (int r = 0; r < 16; ++r) {
    const unsigned int* gp = (const unsigned int*)(wt + (size_t)(r * 128 + tid) * 8);
    unsigned short* lp = dst + (size_t)(r * 128 + w * 64) * 8;
    __builtin_amdgcn_global_load_lds(
        (const __attribute__((address_space(1))) unsigned int*)gp,
        (__attribute__((address_space(3))) unsigned int*)lp, 16, 0, 0);
  }
}

__global__ __launch_bounds__(128, 1) void adaptive_attn_kernel(
    const float* __restrict__ qg, const unsigned short* __restrict__ ws,
    const float* __restrict__ alphap, float* __restrict__ out) {
  __shared__ unsigned short sBuf[2][TILE_USH];   // 64 KB double buffer
  __shared__ unsigned short sP[NW][NH][1024];    // 16 KB: per wave/half, XOR-swizzled
  // 80 KB total -> 2 blocks/CU on 160KB LDS (4 waves/CU; LDS-bound)

  const int b    = blockIdx.x;                   // 512 blocks
  const int head = (b & 7) * 4 + ((b >> 3) & 3); // XCD L2 locality swizzle
  const int qt   = b >> 5;                       // 0..15

  const int tid  = threadIdx.x;
  const int w    = tid >> 6;                     // 0..1
  const int lane = tid & 63;
  const int g    = lane >> 4;
  const int qi   = lane & 15;

  const float lscale = alphap[0] * 1.44269504088896f;  // alpha * log2(e)

  // Q fragments (B-operand layout) for all 4 query halves, fp16(lscale*Q).
  f16x8 qf[NH][4];                               // 64 VGPR
#pragma unroll
  for (int h = 0; h < NH; ++h) {
    const int qrow = qt * BQ + w * 64 + h * 16 + qi;
    const float* qp = qg + (size_t)head * S_LEN * HD + (size_t)qrow * HD;
#pragma unroll
    for (int c = 0; c < 4; ++c) {
      float4 a  = *(const float4*)(qp + c * 32 + g * 8);
      float4 bb = *(const float4*)(qp + c * 32 + g * 8 + 4);
      float xs[8] = {a.x, a.y, a.z, a.w, bb.x, bb.y, bb.z, bb.w};
      union { f16x8 v; _Float16 s[8]; } hh;
#pragma unroll
      for (int j = 0; j < 8; ++j) hh.s[j] = (_Float16)(xs[j] * lscale);
      qf[h][c] = hh.v;
    }
  }

  f32x4 o[NH][8];                                // 128 VGPR
#pragma unroll
  for (int h = 0; h < NH; ++h)
#pragma unroll
    for (int dt = 0; dt < 8; ++dt) o[h][dt] = (f32x4){0.f, 0.f, 0.f, 0.f};
  float lrun[NH] = {0.f, 0.f, 0.f, 0.f};

  const unsigned short* wsh = ws + (size_t)head * NT * TILE_USH;

  // Prologue: stage tile 0 into buffer 0.
  stage_tile(wsh, &sBuf[0][0], tid, w);
  __syncthreads();

  for (int kt = 0; kt < NT; ++kt) {
    const unsigned short* sK  = &sBuf[kt & 1][0];
    const unsigned short* sVt = sK + 8192;

    // Prefetch next tile; its vmcnt drain hides behind compute.
    if (kt + 1 < NT)
      stage_tile(wsh + (size_t)(kt + 1) * TILE_USH, &sBuf[(kt + 1) & 1][0], tid, w);

    // S^T (64 keys x 64 queries), mt-outer / half-inner: each K fragment read
    // feeds 4 MFMAs; st transient is only 16 VGPRs per mt. key&7 == qi&7.
#pragma unroll
    for (int mt = 0; mt < 4; ++mt) {
      f32x4 acc[NH];
#pragma unroll
      for (int h = 0; h < NH; ++h) acc[h] = (f32x4){0.f, 0.f, 0.f, 0.f};
#pragma unroll
      for (int c = 0; c < 4; ++c) {
        int ch   = c * 4 + g;
        int slot = (ch & 8) | ((ch & 7) ^ (qi & 7));
        f16x8 ah = *(const f16x8*)&sK[(mt * 16 + qi) * 128 + slot * 8];
        acc[0] = __builtin_amdgcn_mfma_f32_16x16x32_f16(ah, qf[0][c], acc[0], 0, 0, 0);
        acc[1] = __builtin_amdgcn_mfma_f32_16x16x32_f16(ah, qf[1][c], acc[1], 0, 0, 0);
        acc[2] = __builtin_amdgcn_mfma_f32_16x16x32_f16(ah, qf[2][c], acc[2], 0, 0, 0);
        acc[3] = __builtin_amdgcn_mfma_f32_16x16x32_f16(ah, qf[3][c], acc[3], 0, 0, 0);
      }
      // Unnormalized softmax for this 16-key block, all 4 halves.
      // P^T -> A-layout via per-wave per-half XOR-swizzled LDS staging:
      // write granule gr = mt*2+(g>>1), sub = g&1, slot = gr ^ (qi&7).
#pragma unroll
      for (int h = 0; h < NH; ++h) {
        float p0 = fast_exp2(acc[h][0]);
        float p1 = fast_exp2(acc[h][1]);
        float p2 = fast_exp2(acc[h][2]);
        float p3 = fast_exp2(acc[h][3]);
        lrun[h] += (p0 + p1) + (p2 + p3);
        bf16x4 pv4;
        pv4[0] = (__bf16)p0; pv4[1] = (__bf16)p1;
        pv4[2] = (__bf16)p2; pv4[3] = (__bf16)p3;
        int slot = (mt * 2 + (g >> 1)) ^ (qi & 7);
        *(bf16x4*)&sP[w][h][qi * 64 + slot * 8 + (g & 1) * 4] = pv4;
      }
    }

    // P fragments (same-wave LDS round trip; no barrier needed).
    bf16x8 pf[NH][2];                            // 32 VGPR
#pragma unroll
    for (int h = 0; h < NH; ++h)
#pragma unroll
      for (int c = 0; c < 2; ++c) {
        int slot = (c * 4 + g) ^ (qi & 7);   // read granule = c*4+g (8 keys)
        pf[h][c] = *(const bf16x8*)&sP[w][h][qi * 64 + slot * 8];
      }

    // PV: each V fragment read feeds 4 MFMAs (all query halves).
#pragma unroll
    for (int dt = 0; dt < 8; ++dt) {
#pragma unroll
      for (int c = 0; c < 2; ++c) {
        int slot = (c * 4 + g) ^ (qi & 7);   // dim&7 == qi&7
        bf16x8 vf = *(const bf16x8*)&sVt[(dt * 16 + qi) * 64 + slot * 8];
        o[0][dt] = __builtin_amdgcn_mfma_f32_16x16x32_bf16(pf[0][c], vf, o[0][dt], 0, 0, 0);
        o[1][dt] = __builtin_amdgcn_mfma_f32_16x16x32_bf16(pf[1][c], vf, o[1][dt], 0, 0, 0);
        o[2][dt] = __builtin_amdgcn_mfma_f32_16x16x32_bf16(pf[2][c], vf, o[2][dt], 0, 0, 0);
        o[3][dt] = __builtin_amdgcn_mfma_f32_16x16x32_bf16(pf[3][c], vf, o[3][dt], 0, 0, 0);
      }
    }

    // One barrier per iteration: (a) all reads of buf[kt&1] done before
    // iteration kt+1 prefetches kt+2 into it; (b) drains the kt+1 DMA.
    __syncthreads();
  }

  // Epilogue: reduce l across quads, divide, store fp32.
  float* oph = out + (size_t)head * S_LEN * HD + (size_t)(qt * BQ + w * 64) * HD;
#pragma unroll
  for (int h = 0; h < NH; ++h) {
    float ltot = lrun[h];
    ltot += __shfl_xor(ltot, 16, 64);
    ltot += __shfl_xor(ltot, 32, 64);  // lanes with same qi hold l(query qi)
    float inv[4];
#pragma unroll
    for (int r = 0; r < 4; ++r) {
      float lr = __shfl(ltot, g * 4 + r, 64);
      inv[r] = 1.0f / lr;
    }
    float* op = oph + (size_t)(h * 16) * HD;
#pragma unroll
    for (int dt = 0; dt < 8; ++dt) {
#pragma unroll
      for (int r = 0; r < 4; ++r) {
        op[(size_t)(g * 4 + r) * HD + dt * 16 + qi] = o[h][dt][r] * inv[r];
      }
    }
  }
}

extern "C" void kernel_launch(void* const* d_in, const int* in_sizes, int n_in,
                              void* d_out, int out_size, void* d_ws, size_t ws_size,
                              hipStream_t stream) {
  const float* q     = (const float*)d_in[0];
  const float* k     = (const float*)d_in[1];
  const float* v     = (const float*)d_in[2];
  const float* alpha = (const float*)d_in[3];
  float* out = (float*)d_out;
  unsigned short* ws = (unsigned short*)d_ws;   // needs 32 MB

  hipLaunchKernelGGL(attn_prepass_kernel, dim3(1024), dim3(256), 0, stream,
                     k, v, ws);
  hipLaunchKernelGGL(adaptive_attn_kernel, dim3(512), dim3(128), 0, stream,
                     q, ws, alpha, out);
}

// Round 6
// 222.151 us; speedup vs baseline: 1.0266x; 1.0266x over previous
//
#include <hip/hip_runtime.h>

// AdaptiveAttention: softmax is shift-invariant along the reduced axis, so
// out = softmax(alpha * QK^T) @ V. Two kernels:
//  1) prepass: K -> fp16, V -> transposed bf16 (LDS-mediated transpose so both
//     global sides are coalesced), into d_ws as per-(head,kt) 32KB blocks with
//     XOR-swizzled 16B granules (conflict-free MFMA LDS reads).
//  2) attention: KEY-SPLIT WAVE PAIRS. Block = 256 thr = 4 waves = 2 pairs;
//     BQ=64 (32 queries per pair). Within a pair, wave kh handles keys
//     [kh*32, kh*32+32) of every 64-key tile: it reads HALF of K and HALF of
//     V^T from LDS (the dominant pipe at ~64% busy was LDS; each wave
//     previously pulled the full 32KB tile). Partial O/l are reduced across
//     the pair once at kernel end via LDS. This halves LDS-bytes-per-FLOP
//     while KEEPING 8 waves/CU (2/SIMD) -- the round-4 variant got the same
//     traffic cut but at 1 wave/SIMD and regressed on latency exposure.
//     Double-buffered global_load_lds staging, single-pass fp16 QK^T,
//     unnormalized exp2 softmax (logits bounded; /l at the end), bf16 PV
//     (unnormalized p reaches ~2^40: overflows fp16, not bf16), ONE barrier
//     per k-tile.
// ws requirement: 32 heads * 32 ktiles * 32KB = 32 MB.

#define S_LEN 2048
#define HD    128
#define BQ    64             // queries per block (2 pairs x 32)
#define BK    64
#define NT    (S_LEN / BK)   // 32 k-tiles
#define TILE_USH 16384       // 32KB per (head,kt): K 8192 | Vt 8192 ushorts

typedef __bf16    bf16x8 __attribute__((ext_vector_type(8)));
typedef __bf16    bf16x4 __attribute__((ext_vector_type(4)));
typedef _Float16  f16x8  __attribute__((ext_vector_type(8)));
typedef float     f32x4  __attribute__((ext_vector_type(4)));

__device__ __forceinline__ unsigned short f2bf(float x) {
  unsigned u = __builtin_bit_cast(unsigned, x);
  u = (u + 0x7FFFu + ((u >> 16) & 1u)) >> 16;   // RNE
  return (unsigned short)u;
}
__device__ __forceinline__ unsigned short f2h(float x) {
  _Float16 h = (_Float16)x;                      // v_cvt_f16_f32, RNE
  return __builtin_bit_cast(unsigned short, h);
}
__device__ __forceinline__ float fast_exp2(float x) {
#if __has_builtin(__builtin_amdgcn_exp2f)
  return __builtin_amdgcn_exp2f(x);
#else
  return exp2f(x);
#endif
}

// ---------- prepass: convert + transpose + swizzle into ws ----------
__global__ __launch_bounds__(256) void attn_prepass_kernel(
    const float* __restrict__ kg, const float* __restrict__ vg,
    unsigned short* __restrict__ ws) {
  __shared__ float T[64 * 130];         // V staging, stride 130 (b64-aligned)
  const int blk  = blockIdx.x;          // head*32 + kt
  const int head = blk >> 5;
  const int kt   = blk & 31;
  const int tid  = threadIdx.x;
  const size_t hoff = (size_t)head * S_LEN * HD;
  const float* kp = kg + hoff + (size_t)kt * BK * HD;
  const float* vp = vg + hoff + (size_t)kt * BK * HD;
  unsigned short* wsK  = ws + (size_t)blk * TILE_USH;
  unsigned short* wsVt = wsK + 8192;

  // K (fp16): granule (key, ch) = dims [ch*8, ch*8+8) of row key.
  // slot = (ch&8) | ((ch&7) ^ (key&7))  -> conflict-free b128 fragment reads.
#pragma unroll
  for (int it = 0; it < 4; ++it) {
    int idx = it * 256 + tid;           // 0..1023
    int key = idx >> 4;
    int ch  = idx & 15;
    const float* src = kp + key * HD + ch * 8;
    float4 a = *(const float4*)src;
    float4 b = *(const float4*)(src + 4);
    float xs[8] = {a.x, a.y, a.z, a.w, b.x, b.y, b.z, b.w};
    union { unsigned short s[8]; uint4 v; } hi;
#pragma unroll
    for (int j = 0; j < 8; ++j) hi.s[j] = f2h(xs[j]);
    int slot = (ch & 8) | ((ch & 7) ^ (key & 7));
    *(uint4*)&wsK[key * 128 + slot * 8] = hi.v;
  }

  // V^T via LDS: phase 1 -- coalesced float2 loads, contiguous LDS rows.
#pragma unroll
  for (int it = 0; it < 16; ++it) {
    int idx = it * 256 + tid;           // 0..4095 float2 granules
    int key = idx >> 6;                 // 64 float2 per row
    int c2  = idx & 63;
    float2 a = *(const float2*)(vp + (size_t)key * HD + c2 * 2);
    *(float2*)&T[key * 130 + c2 * 2] = a;
  }
  __syncthreads();

  // phase 2 -- column gather from LDS (<=4-way conflicts), coalesced granule
  // writes. granule (dim, ch) = keys [ch*8, ch*8+8) of column dim;
  // slot = ch ^ (dim&7).
#pragma unroll
  for (int r = 0; r < 4; ++r) {
    int idx = r * 256 + tid;            // 0..1023
    int dim = idx >> 3;                 // 0..127
    int ch  = idx & 7;
    union { unsigned short s[8]; uint4 v; } gg;
#pragma unroll
    for (int j = 0; j < 8; ++j) gg.s[j] = f2bf(T[(ch * 8 + j) * 130 + dim]);
    int slot = ch ^ (dim & 7);
    *(uint4*)&wsVt[dim * 64 + slot * 8] = gg.v;
  }
}

// ---------- attention ----------
__device__ __forceinline__ void stage_tile(const unsigned short* __restrict__ wt,
                                           unsigned short* dst, int tid, int w) {
  // 8 rounds x 256 lanes x 16B = 32KB. LDS dest is wave-uniform base (w*64
  // granules) + implicit lane*16B -- the m104/m108 requirement.
#pragma unroll
  for (int r = 0; r < 8; ++r) {
    const unsigned int* gp = (const unsigned int*)(wt + (size_t)(r * 256 + tid) * 8);
    unsigned short* lp = dst + (size_t)(r * 256 + w * 64) * 8;
    __builtin_amdgcn_global_load_lds(
        (const __attribute__((address_space(1))) unsigned int*)gp,
        (__attribute__((address_space(3))) unsigned int*)lp, 16, 0, 0);
  }
}

__global__ __launch_bounds__(256, 2) void adaptive_attn_kernel(
    const float* __restrict__ qg, const unsigned short* __restrict__ ws,
    const float* __restrict__ alphap, float* __restrict__ out) {
  __shared__ unsigned short sBuf[2][TILE_USH];   // 64 KB double buffer
  __shared__ unsigned short sP[4][2][512];       // 8 KB: [wave][half][16qi x 32key]
  __shared__ float sL[2][2][16];                 // [qp][h][qi]: kh=1 partial l
  // 72.5 KB total -> 2 blocks/CU (8 waves, 2/SIMD)

  const int b    = blockIdx.x;                   // 1024 blocks
  const int head = (b & 7) * 4 + ((b >> 3) & 3); // XCD L2 locality swizzle
  const int qt   = b >> 5;                       // 0..31

  const int tid  = threadIdx.x;
  const int w    = tid >> 6;                     // 0..3
  const int qp   = w >> 1;                       // query pair within block
  const int kh   = w & 1;                        // key half this wave owns
  const int lane = tid & 63;
  const int g    = lane >> 4;
  const int qi   = lane & 15;

  const float lscale = alphap[0] * 1.44269504088896f;  // alpha * log2(e)

  // Q fragments (B-operand layout) for both query halves, fp16(lscale*Q).
  f16x8 qf[2][4];                                // 32 VGPR
#pragma unroll
  for (int h = 0; h < 2; ++h) {
    const int qrow = qt * BQ + qp * 32 + h * 16 + qi;
    const float* qp_ = qg + (size_t)head * S_LEN * HD + (size_t)qrow * HD;
#pragma unroll
    for (int c = 0; c < 4; ++c) {
      float4 a  = *(const float4*)(qp_ + c * 32 + g * 8);
      float4 bb = *(const float4*)(qp_ + c * 32 + g * 8 + 4);
      float xs[8] = {a.x, a.y, a.z, a.w, bb.x, bb.y, bb.z, bb.w};
      union { f16x8 v; _Float16 s[8]; } hh;
#pragma unroll
      for (int j = 0; j < 8; ++j) hh.s[j] = (_Float16)(xs[j] * lscale);
      qf[h][c] = hh.v;
    }
  }

  f32x4 o[2][8];                                 // 64 VGPR (partial: our keys)
#pragma unroll
  for (int h = 0; h < 2; ++h)
#pragma unroll
    for (int dt = 0; dt < 8; ++dt) o[h][dt] = (f32x4){0.f, 0.f, 0.f, 0.f};
  float lrun[2] = {0.f, 0.f};

  const unsigned short* wsh = ws + (size_t)head * NT * TILE_USH;

  // Prologue: stage tile 0 into buffer 0.
  stage_tile(wsh, &sBuf[0][0], tid, w);
  __syncthreads();

  for (int kt = 0; kt < NT; ++kt) {
    const unsigned short* sK  = &sBuf[kt & 1][0];
    const unsigned short* sVt = sK + 8192;

    // Prefetch next tile; its vmcnt drain hides behind the whole iteration.
    if (kt + 1 < NT)
      stage_tile(wsh + (size_t)(kt + 1) * TILE_USH, &sBuf[(kt + 1) & 1][0], tid, w);

    // S^T for OUR 32 keys x 32 queries: global key row = (kh*2+mt)*16+qi.
    // key&7 == qi&7, so the prepass swizzle stays conflict-free.
    f32x4 st[2][2];
#pragma unroll
    for (int mt = 0; mt < 2; ++mt) {
      f32x4 a0 = (f32x4){0.f, 0.f, 0.f, 0.f};
      f32x4 a1 = (f32x4){0.f, 0.f, 0.f, 0.f};
      const int keyrow = (kh * 2 + mt) * 16 + qi;
#pragma unroll
      for (int c = 0; c < 4; ++c) {
        int ch   = c * 4 + g;
        int slot = (ch & 8) | ((ch & 7) ^ (qi & 7));
        f16x8 ah = *(const f16x8*)&sK[keyrow * 128 + slot * 8];
        a0 = __builtin_amdgcn_mfma_f32_16x16x32_f16(ah, qf[0][c], a0, 0, 0, 0);
        a1 = __builtin_amdgcn_mfma_f32_16x16x32_f16(ah, qf[1][c], a1, 0, 0, 0);
      }
      st[0][mt] = a0; st[1][mt] = a1;
    }

    // Unnormalized softmax for our keys; private per-wave sP (same-wave LDS
    // round trip -- no barrier). Local key = mt*16 + g*4 + r; granule
    // gl = mt*2+(g>>1); slot = gl ^ (qi&3) (4-way on a tiny volume).
#pragma unroll
    for (int h = 0; h < 2; ++h) {
      unsigned short* sPh = &sP[w][h][0];
#pragma unroll
      for (int mt = 0; mt < 2; ++mt) {
        float p0 = fast_exp2(st[h][mt][0]);
        float p1 = fast_exp2(st[h][mt][1]);
        float p2 = fast_exp2(st[h][mt][2]);
        float p3 = fast_exp2(st[h][mt][3]);
        lrun[h] += (p0 + p1) + (p2 + p3);
        bf16x4 pv4;
        pv4[0] = (__bf16)p0; pv4[1] = (__bf16)p1;
        pv4[2] = (__bf16)p2; pv4[3] = (__bf16)p3;
        int slot = (mt * 2 + (g >> 1)) ^ (qi & 3);
        *(bf16x4*)&sPh[qi * 32 + slot * 8 + (g & 1) * 4] = pv4;
      }
    }

    // P fragment: lane needs local keys g*8..g*8+8 -> granule g.
    bf16x8 pf[2];
#pragma unroll
    for (int h = 0; h < 2; ++h) {
      int slot = g ^ (qi & 3);
      pf[h] = *(const bf16x8*)&sP[w][h][qi * 32 + slot * 8];
    }

    // PV over our key half: V^T granule ch = kh*4+g (keys kh*32+g*8..+8).
    // All 8 dt blocks; partial O accumulates over our keys only.
#pragma unroll
    for (int dt = 0; dt < 8; ++dt) {
      int slot = (kh * 4 + g) ^ (qi & 7);   // dim&7 == qi&7
      bf16x8 vf = *(const bf16x8*)&sVt[(dt * 16 + qi) * 64 + slot * 8];
      o[0][dt] = __builtin_amdgcn_mfma_f32_16x16x32_bf16(pf[0], vf, o[0][dt], 0, 0, 0);
      o[1][dt] = __builtin_amdgcn_mfma_f32_16x16x32_bf16(pf[1], vf, o[1][dt], 0, 0, 0);
    }

    // One barrier per iteration: (a) all reads of buf[kt&1] done before
    // iteration kt+1 prefetches kt+2 into it; (b) drains the kt+1 DMA.
    __syncthreads();
  }

  // Epilogue: pair reduction (kh=1 -> kh=0) of partial O and l via LDS,
  // then normalize + store. sBuf is dead; reuse as the O exchange buffer.
  float lt[2];
#pragma unroll
  for (int h = 0; h < 2; ++h) {
    float t = lrun[h];
    t += __shfl_xor(t, 16, 64);
    t += __shfl_xor(t, 32, 64);   // lanes with same qi hold partial l(qi)
    lt[h] = t;
  }

  float* sRed = (float*)&sBuf[0][0];    // 2 pairs x 16 KB
  if (kh == 1) {
#pragma unroll
    for (int h = 0; h < 2; ++h) {
#pragma unroll
      for (int dt = 0; dt < 8; ++dt)
#pragma unroll
        for (int r = 0; r < 4; ++r)
          sRed[qp * 4096 + ((h * 8 + dt) * 4 + r) * 64 + lane] = o[h][dt][r];
      if (lane < 16) sL[qp][h][qi] = lt[h];
    }
  }
  __syncthreads();

  if (kh == 0) {
    float* oph = out + (size_t)head * S_LEN * HD + (size_t)(qt * BQ + qp * 32) * HD;
#pragma unroll
    for (int h = 0; h < 2; ++h) {
      float comb = lt[h] + sL[qp][h][qi];
      float inv[4];
#pragma unroll
      for (int r = 0; r < 4; ++r) {
        float lr = __shfl(comb, g * 4 + r, 64);
        inv[r] = 1.0f / lr;
      }
      float* op = oph + (size_t)(h * 16) * HD;
#pragma unroll
      for (int dt = 0; dt < 8; ++dt) {
#pragma unroll
        for (int r = 0; r < 4; ++r) {
          float val = o[h][dt][r] + sRed[qp * 4096 + ((h * 8 + dt) * 4 + r) * 64 + lane];
          op[(size_t)(g * 4 + r) * HD + dt * 16 + qi] = val * inv[r];
        }
      }
    }
  }
}

extern "C" void kernel_launch(void* const* d_in, const int* in_sizes, int n_in,
                              void* d_out, int out_size, void* d_ws, size_t ws_size,
                              hipStream_t stream) {
  const float* q     = (const float*)d_in[0];
  const float* k     = (const float*)d_in[1];
  const float* v     = (const float*)d_in[2];
  const float* alpha = (const float*)d_in[3];
  float* out = (float*)d_out;
  unsigned short* ws = (unsigned short*)d_ws;   // needs 32 MB

  hipLaunchKernelGGL(attn_prepass_kernel, dim3(1024), dim3(256), 0, stream,
                     k, v, ws);
  hipLaunchKernelGGL(adaptive_attn_kernel, dim3(1024), dim3(256), 0, stream,
                     q, ws, alpha, out);
}

// Round 7
// 220.794 us; speedup vs baseline: 1.0329x; 1.0061x over previous
//
#include <hip/hip_runtime.h>

// AdaptiveAttention: softmax is shift-invariant along the reduced axis, so
// out = softmax(alpha * QK^T) @ V. Two kernels:
//  1) prepass: K -> fp16, V -> transposed bf16 (LDS-mediated transpose so both
//     global sides are coalesced), into d_ws as per-(head,kt32) 16KB records
//     [K: 32keys x 128][Vt: 128dims x 32keys] with XOR-swizzled 16B granules
//     (conflict-free MFMA LDS reads).
//  2) attention: round-1 per-wave structure (32 queries/wave, 2 halves,
//     single-pass fp16 QK^T, unnormalized exp2 softmax, bf16 PV) but with
//     BK=32 k-tiles and 2-wave blocks: LDS = 2x16KB dbuf + 8KB sP = 40KB ->
//     4 blocks/CU = 4 INDEPENDENT BARRIER DOMAINS (was 2) with 2-wave joins
//     (was 4) and 64 fine iterations (was 32). Rounds 3/4/6 showed traffic
//     cuts that break V-sharing/occupancy/conflict-freedom all regress; this
//     changes ONLY barrier-domain granularity: per-key LDS traffic, MFMA
//     count, swizzle conflict-freedom, and L2 locality are identical to the
//     91us round-1 kernel.
// ws requirement: 32 heads * 64 ktiles * 16KB = 32 MB.

#define S_LEN 2048
#define HD    128
#define BQ    64             // queries per block (2 waves x 32)
#define BK    32
#define NT    (S_LEN / BK)   // 64 k-tiles
#define REC_USH 8192         // 16KB per (head,kt32): K 4096 | Vt 4096 ushorts

typedef __bf16    bf16x8 __attribute__((ext_vector_type(8)));
typedef __bf16    bf16x4 __attribute__((ext_vector_type(4)));
typedef _Float16  f16x8  __attribute__((ext_vector_type(8)));
typedef float     f32x4  __attribute__((ext_vector_type(4)));

__device__ __forceinline__ unsigned short f2bf(float x) {
  unsigned u = __builtin_bit_cast(unsigned, x);
  u = (u + 0x7FFFu + ((u >> 16) & 1u)) >> 16;   // RNE
  return (unsigned short)u;
}
__device__ __forceinline__ unsigned short f2h(float x) {
  _Float16 h = (_Float16)x;                      // v_cvt_f16_f32, RNE
  return __builtin_bit_cast(unsigned short, h);
}
__device__ __forceinline__ float fast_exp2(float x) {
#if __has_builtin(__builtin_amdgcn_exp2f)
  return __builtin_amdgcn_exp2f(x);
#else
  return exp2f(x);
#endif
}

// ---------- prepass: convert + transpose + swizzle into ws ----------
__global__ __launch_bounds__(256) void attn_prepass_kernel(
    const float* __restrict__ kg, const float* __restrict__ vg,
    unsigned short* __restrict__ ws) {
  __shared__ float T[64 * 130];         // V staging, stride 130 (b64-aligned)
  const int blk  = blockIdx.x;          // head*32 + kt64  (64 keys each)
  const int head = blk >> 5;
  const int kt   = blk & 31;
  const int tid  = threadIdx.x;
  const size_t hoff = (size_t)head * S_LEN * HD;
  const float* kp = kg + hoff + (size_t)kt * 64 * HD;
  const float* vp = vg + hoff + (size_t)kt * 64 * HD;
  // two 16KB records: keys 0..31 -> rec0, keys 32..63 -> rec1
  unsigned short* rec0 = ws + ((size_t)head * NT + kt * 2) * REC_USH;
  unsigned short* rec1 = rec0 + REC_USH;

  // K (fp16): granule (key, ch) = dims [ch*8, ch*8+8) of row key.
  // slot = (ch&8) | ((ch&7) ^ (key&7))  -> conflict-free b128 fragment reads.
#pragma unroll
  for (int it = 0; it < 4; ++it) {
    int idx = it * 256 + tid;           // 0..1023
    int key = idx >> 4;                 // 0..63
    int ch  = idx & 15;
    const float* src = kp + key * HD + ch * 8;
    float4 a = *(const float4*)src;
    float4 b = *(const float4*)(src + 4);
    float xs[8] = {a.x, a.y, a.z, a.w, b.x, b.y, b.z, b.w};
    union { unsigned short s[8]; uint4 v; } hi;
#pragma unroll
    for (int j = 0; j < 8; ++j) hi.s[j] = f2h(xs[j]);
    int slot = (ch & 8) | ((ch & 7) ^ (key & 7));
    unsigned short* wsK = (key < 32) ? rec0 : rec1;
    *(uint4*)&wsK[(key & 31) * 128 + slot * 8] = hi.v;
  }

  // V^T via LDS: phase 1 -- coalesced float2 loads, contiguous LDS rows.
#pragma unroll
  for (int it = 0; it < 16; ++it) {
    int idx = it * 256 + tid;           // 0..4095 float2 granules
    int key = idx >> 6;                 // 64 float2 per row
    int c2  = idx & 63;
    float2 a = *(const float2*)(vp + (size_t)key * HD + c2 * 2);
    *(float2*)&T[key * 130 + c2 * 2] = a;
  }
  __syncthreads();

  // phase 2 -- column gather from LDS, granule (dim, ch) = keys
  // [ch*8, ch*8+8) of column dim. Record = ch>>2; within record,
  // slot = (ch&3) ^ ((dim>>1)&3)  (<=2-way banks on the attn-side read).
#pragma unroll
  for (int r = 0; r < 4; ++r) {
    int idx = r * 256 + tid;            // 0..1023
    int dim = idx >> 3;                 // 0..127
    int ch  = idx & 7;
    union { unsigned short s[8]; uint4 v; } gg;
#pragma unroll
    for (int j = 0; j < 8; ++j) gg.s[j] = f2bf(T[(ch * 8 + j) * 130 + dim]);
    int slot = (ch & 3) ^ ((dim >> 1) & 3);
    unsigned short* wsVt = ((ch < 4) ? rec0 : rec1) + 4096;
    *(uint4*)&wsVt[dim * 32 + slot * 8] = gg.v;
  }
}

// ---------- attention ----------
__device__ __forceinline__ void stage_rec(const unsigned short* __restrict__ wt,
                                          unsigned short* dst, int tid, int w) {
  // 8 rounds x 128 lanes x 16B = 16KB. LDS dest is wave-uniform base (w*64
  // granules) + implicit lane*16B -- the m104/m108 requirement.
#pragma unroll
  for (int r = 0; r < 8; ++r) {
    const unsigned int* gp = (const unsigned int*)(wt + (size_t)(r * 128 + tid) * 8);
    unsigned short* lp = dst + (size_t)(r * 128 + w * 64) * 8;
    __builtin_amdgcn_global_load_lds(
        (const __attribute__((address_space(1))) unsigned int*)gp,
        (__attribute__((address_space(3))) unsigned int*)lp, 16, 0, 0);
  }
}

__global__ __launch_bounds__(128, 2) void adaptive_attn_kernel(
    const float* __restrict__ qg, const unsigned short* __restrict__ ws,
    const float* __restrict__ alphap, float* __restrict__ out) {
  __shared__ unsigned short sBuf[2][REC_USH];    // 32 KB double buffer
  __shared__ unsigned short sP[2][2][1024];      // 8 KB: [wave][half], 16x64 rows
  // 40 KB total -> 4 blocks/CU = 4 barrier domains (8 waves/CU)

  const int b    = blockIdx.x;                   // 1024 blocks
  const int head = (b & 7) * 4 + ((b >> 3) & 3); // XCD L2 locality swizzle
  const int qt   = b >> 5;                       // 0..31

  const int tid  = threadIdx.x;
  const int w    = tid >> 6;                     // 0..1
  const int lane = tid & 63;
  const int g    = lane >> 4;
  const int qi   = lane & 15;

  const float lscale = alphap[0] * 1.44269504088896f;  // alpha * log2(e)

  // Q fragments (B-operand layout) for both query halves, fp16(lscale*Q).
  f16x8 qf[2][4];                                // 32 VGPR
#pragma unroll
  for (int h = 0; h < 2; ++h) {
    const int qrow = qt * BQ + w * 32 + h * 16 + qi;
    const float* qp = qg + (size_t)head * S_LEN * HD + (size_t)qrow * HD;
#pragma unroll
    for (int c = 0; c < 4; ++c) {
      float4 a  = *(const float4*)(qp + c * 32 + g * 8);
      float4 bb = *(const float4*)(qp + c * 32 + g * 8 + 4);
      float xs[8] = {a.x, a.y, a.z, a.w, bb.x, bb.y, bb.z, bb.w};
      union { f16x8 v; _Float16 s[8]; } hh;
#pragma unroll
      for (int j = 0; j < 8; ++j) hh.s[j] = (_Float16)(xs[j] * lscale);
      qf[h][c] = hh.v;
    }
  }

  f32x4 o[2][8];                                 // 64 VGPR
#pragma unroll
  for (int h = 0; h < 2; ++h)
#pragma unroll
    for (int dt = 0; dt < 8; ++dt) o[h][dt] = (f32x4){0.f, 0.f, 0.f, 0.f};
  float lrun[2] = {0.f, 0.f};

  const unsigned short* wsh = ws + (size_t)head * NT * REC_USH;

  // Prologue: stage record 0 into buffer 0.
  stage_rec(wsh, &sBuf[0][0], tid, w);
  __syncthreads();

  for (int kt = 0; kt < NT; ++kt) {
    const unsigned short* sK  = &sBuf[kt & 1][0];
    const unsigned short* sVt = sK + 4096;

    // Prefetch next record; its vmcnt drain hides behind the iteration.
    if (kt + 1 < NT)
      stage_rec(wsh + (size_t)(kt + 1) * REC_USH, &sBuf[(kt + 1) & 1][0], tid, w);

    // S^T (32 keys x 32 queries): each K fragment read feeds 2 MFMAs
    // (2 query halves). key&7 == qi&7 since key = mt*16+qi.
    f32x4 st[2][2];
#pragma unroll
    for (int mt = 0; mt < 2; ++mt) {
      f32x4 a0 = (f32x4){0.f, 0.f, 0.f, 0.f};
      f32x4 a1 = (f32x4){0.f, 0.f, 0.f, 0.f};
#pragma unroll
      for (int c = 0; c < 4; ++c) {
        int ch   = c * 4 + g;
        int slot = (ch & 8) | ((ch & 7) ^ (qi & 7));
        f16x8 ah = *(const f16x8*)&sK[(mt * 16 + qi) * 128 + slot * 8];
        a0 = __builtin_amdgcn_mfma_f32_16x16x32_f16(ah, qf[0][c], a0, 0, 0, 0);
        a1 = __builtin_amdgcn_mfma_f32_16x16x32_f16(ah, qf[1][c], a1, 0, 0, 0);
      }
      st[0][mt] = a0; st[1][mt] = a1;
    }

    // Unnormalized softmax: p = exp2(st) (bounded logits; /l at the end).
    // P^T -> A-layout via per-wave per-half XOR-swizzled LDS staging:
    // granule gl = mt*2+(g>>1) in 0..3, slot = gl ^ (qi&7) in 0..7
    // (64-ush rows keep the proven conflict-free bank rotation).
#pragma unroll
    for (int h = 0; h < 2; ++h) {
      unsigned short* sPh = &sP[w][h][0];
#pragma unroll
      for (int mt = 0; mt < 2; ++mt) {
        float p0 = fast_exp2(st[h][mt][0]);
        float p1 = fast_exp2(st[h][mt][1]);
        float p2 = fast_exp2(st[h][mt][2]);
        float p3 = fast_exp2(st[h][mt][3]);
        lrun[h] += (p0 + p1) + (p2 + p3);
        bf16x4 pv4;
        pv4[0] = (__bf16)p0; pv4[1] = (__bf16)p1;
        pv4[2] = (__bf16)p2; pv4[3] = (__bf16)p3;
        int slot = (mt * 2 + (g >> 1)) ^ (qi & 7);
        *(bf16x4*)&sPh[qi * 64 + slot * 8 + (g & 1) * 4] = pv4;
      }
    }

    // P fragment: lane needs keys g*8..g*8+7 -> granule g, slot = g^(qi&7).
    bf16x8 pf[2];
#pragma unroll
    for (int h = 0; h < 2; ++h) {
      int slot = g ^ (qi & 7);
      pf[h] = *(const bf16x8*)&sP[w][h][qi * 64 + slot * 8];
    }

    // PV: 32-key tile -> one A-fragment per half; each V fragment read
    // feeds 2 MFMAs. V slot = g ^ ((qi>>1)&3)  (matches prepass placement).
#pragma unroll
    for (int dt = 0; dt < 8; ++dt) {
      int slot = g ^ ((qi >> 1) & 3);
      bf16x8 vf = *(const bf16x8*)&sVt[(dt * 16 + qi) * 32 + slot * 8];
      o[0][dt] = __builtin_amdgcn_mfma_f32_16x16x32_bf16(pf[0], vf, o[0][dt], 0, 0, 0);
      o[1][dt] = __builtin_amdgcn_mfma_f32_16x16x32_bf16(pf[1], vf, o[1][dt], 0, 0, 0);
    }

    // One barrier per iteration: (a) all reads of buf[kt&1] done before
    // iteration kt+1 prefetches kt+2 into it; (b) drains the kt+1 DMA
    // (issued a full iteration earlier, so the drain is cheap).
    __syncthreads();
  }

  // Epilogue: reduce l across quads, divide, store fp32.
  float* oph = out + (size_t)head * S_LEN * HD + (size_t)(qt * BQ + w * 32) * HD;
#pragma unroll
  for (int h = 0; h < 2; ++h) {
    float ltot = lrun[h];
    ltot += __shfl_xor(ltot, 16, 64);
    ltot += __shfl_xor(ltot, 32, 64);  // lanes with same qi hold l(query qi)
    float inv[4];
#pragma unroll
    for (int r = 0; r < 4; ++r) {
      float lr = __shfl(ltot, g * 4 + r, 64);
      inv[r] = 1.0f / lr;
    }
    float* op = oph + (size_t)(h * 16) * HD;
#pragma unroll
    for (int dt = 0; dt < 8; ++dt) {
#pragma unroll
      for (int r = 0; r < 4; ++r) {
        op[(size_t)(g * 4 + r) * HD + dt * 16 + qi] = o[h][dt][r] * inv[r];
      }
    }
  }
}

extern "C" void kernel_launch(void* const* d_in, const int* in_sizes, int n_in,
                              void* d_out, int out_size, void* d_ws, size_t ws_size,
                              hipStream_t stream) {
  const float* q     = (const float*)d_in[0];
  const float* k     = (const float*)d_in[1];
  const float* v     = (const float*)d_in[2];
  const float* alpha = (const float*)d_in[3];
  float* out = (float*)d_out;
  unsigned short* ws = (unsigned short*)d_ws;   // needs 32 MB

  hipLaunchKernelGGL(attn_prepass_kernel, dim3(1024), dim3(256), 0, stream,
                     k, v, ws);
  hipLaunchKernelGGL(adaptive_attn_kernel, dim3(1024), dim3(128), 0, stream,
                     q, ws, alpha, out);
}

// Round 8
// 194.352 us; speedup vs baseline: 1.1734x; 1.1361x over previous
//
#include <hip/hip_runtime.h>

// AdaptiveAttention: softmax is shift-invariant along the reduced axis, so
// out = softmax(alpha * QK^T) @ V. Two kernels:
//  1) prepass: K -> fp16, V -> transposed bf16 (LDS-mediated transpose so both
//     global sides are coalesced), into d_ws as per-(head,kt) 32KB blocks with
//     XOR-swizzled 16B granules (conflict-free MFMA LDS reads).
//  2) attention: BQ=128 (4 waves x 32 queries, 2 query-halves each).
//     Double-buffered global_load_lds staging, single-pass fp16 QK^T,
//     unnormalized exp2 softmax (logits bounded; /l at the end), bf16 PV
//     (unnormalized p reaches ~2^40: overflows fp16, not bf16).
//     P^T -> A-fragment redistribution is done ENTIRELY IN REGISTERS via
//     v_cvt_pk_bf16_f32 + v_permlane32_swap + v_permlane16_swap (VALU pipe)
//     instead of an LDS round trip: the old sP b64 writes were 100% of
//     SQ_LDS_BANK_CONFLICT (6.29M = exactly 12 cyc x 524288 writes) on the
//     busiest pipe. Lane (g,qi) needs P from lanes {qi,qi+16,qi+32,qi+48};
//     with A={a0,a1,a2,a3},B={b0,b1,b2,b3} as 16-lane row groups, the needed
//     words {a0,a2,b0,b2} / {a1,a3,b1,b3} are one permlane32_swap then one
//     permlane16_swap (perfect shuffle).
// ws requirement: 32 heads * 32 ktiles * 32KB = 32 MB.

#define S_LEN 2048
#define HD    128
#define BQ    128
#define BK    64
#define NW    4
#define NT    (S_LEN / BK)   // 32 k-tiles
#define TILE_USH 16384       // 32KB per (head,kt): K 8192 | Vt 8192 ushorts

typedef __bf16    bf16x8 __attribute__((ext_vector_type(8)));
typedef _Float16  f16x8  __attribute__((ext_vector_type(8)));
typedef float     f32x4  __attribute__((ext_vector_type(4)));
typedef unsigned  uint2v __attribute__((ext_vector_type(2)));
typedef unsigned  uint4v __attribute__((ext_vector_type(4)));

__device__ __forceinline__ unsigned short f2bf(float x) {
  unsigned u = __builtin_bit_cast(unsigned, x);
  u = (u + 0x7FFFu + ((u >> 16) & 1u)) >> 16;   // RNE
  return (unsigned short)u;
}
__device__ __forceinline__ unsigned short f2h(float x) {
  _Float16 h = (_Float16)x;                      // v_cvt_f16_f32, RNE
  return __builtin_bit_cast(unsigned short, h);
}
__device__ __forceinline__ float fast_exp2(float x) {
#if __has_builtin(__builtin_amdgcn_exp2f)
  return __builtin_amdgcn_exp2f(x);
#else
  return exp2f(x);
#endif
}
// pack two f32 -> {bf16(lo), bf16(hi)} in one u32 (no builtin on gfx950)
__device__ __forceinline__ unsigned cvt_pk_bf16(float lo, float hi) {
  unsigned r;
  asm("v_cvt_pk_bf16_f32 %0, %1, %2" : "=v"(r) : "v"(lo), "v"(hi));
  return r;
}
// x,y as 16-lane rows {x0,x1,x2,x3},{y0,y1,y2,y3}:
// swap32: x'={x0,x1,y0,y1}, y'={x2,x3,y2,y3}
__device__ __forceinline__ void swap32(unsigned &x, unsigned &y) {
#if __has_builtin(__builtin_amdgcn_permlane32_swap)
  uint2v r = __builtin_amdgcn_permlane32_swap(x, y, false, false);
  x = r[0]; y = r[1];
#else
  asm("v_permlane32_swap_b32 %0, %1" : "+v"(x), "+v"(y));
#endif
}
// swap16: x'={x0,y0,x2,y2}, y'={x1,y1,x3,y3}
__device__ __forceinline__ void swap16(unsigned &x, unsigned &y) {
#if __has_builtin(__builtin_amdgcn_permlane16_swap)
  uint2v r = __builtin_amdgcn_permlane16_swap(x, y, false, false);
  x = r[0]; y = r[1];
#else
  asm("v_permlane16_swap_b32 %0, %1" : "+v"(x), "+v"(y));
#endif
}

// ---------- prepass: convert + transpose + swizzle into ws ----------
__global__ __launch_bounds__(256) void attn_prepass_kernel(
    const float* __restrict__ kg, const float* __restrict__ vg,
    unsigned short* __restrict__ ws) {
  __shared__ float T[64 * 130];         // V staging, stride 130 (b64-aligned)
  const int blk  = blockIdx.x;          // head*32 + kt
  const int head = blk >> 5;
  const int kt   = blk & 31;
  const int tid  = threadIdx.x;
  const size_t hoff = (size_t)head * S_LEN * HD;
  const float* kp = kg + hoff + (size_t)kt * BK * HD;
  const float* vp = vg + hoff + (size_t)kt * BK * HD;
  unsigned short* wsK  = ws + (size_t)blk * TILE_USH;
  unsigned short* wsVt = wsK + 8192;

  // K (fp16): granule (key, ch) = dims [ch*8, ch*8+8) of row key.
  // slot = (ch&8) | ((ch&7) ^ (key&7))  -> conflict-free b128 fragment reads.
#pragma unroll
  for (int it = 0; it < 4; ++it) {
    int idx = it * 256 + tid;           // 0..1023
    int key = idx >> 4;
    int ch  = idx & 15;
    const float* src = kp + key * HD + ch * 8;
    float4 a = *(const float4*)src;
    float4 b = *(const float4*)(src + 4);
    float xs[8] = {a.x, a.y, a.z, a.w, b.x, b.y, b.z, b.w};
    union { unsigned short s[8]; uint4 v; } hi;
#pragma unroll
    for (int j = 0; j < 8; ++j) hi.s[j] = f2h(xs[j]);
    int slot = (ch & 8) | ((ch & 7) ^ (key & 7));
    *(uint4*)&wsK[key * 128 + slot * 8] = hi.v;
  }

  // V^T via LDS: phase 1 -- coalesced float2 loads, contiguous LDS rows.
#pragma unroll
  for (int it = 0; it < 16; ++it) {
    int idx = it * 256 + tid;           // 0..4095 float2 granules
    int key = idx >> 6;                 // 64 float2 per row
    int c2  = idx & 63;
    float2 a = *(const float2*)(vp + (size_t)key * HD + c2 * 2);
    *(float2*)&T[key * 130 + c2 * 2] = a;
  }
  __syncthreads();

  // phase 2 -- column gather from LDS (<=4-way conflicts), coalesced granule
  // writes. granule (dim, ch) = keys [ch*8, ch*8+8) of column dim;
  // slot = ch ^ (dim&7).
#pragma unroll
  for (int r = 0; r < 4; ++r) {
    int idx = r * 256 + tid;            // 0..1023
    int dim = idx >> 3;                 // 0..127
    int ch  = idx & 7;
    union { unsigned short s[8]; uint4 v; } gg;
#pragma unroll
    for (int j = 0; j < 8; ++j) gg.s[j] = f2bf(T[(ch * 8 + j) * 130 + dim]);
    int slot = ch ^ (dim & 7);
    *(uint4*)&wsVt[dim * 64 + slot * 8] = gg.v;
  }
}

// ---------- attention ----------
__device__ __forceinline__ void stage_tile(const unsigned short* __restrict__ wt,
                                           unsigned short* dst, int tid, int w) {
  // 8 rounds x 256 lanes x 16B = 32KB. LDS dest is wave-uniform base (w*64
  // granules) + implicit lane*16B -- the m104/m108 requirement.
#pragma unroll
  for (int r = 0; r < 8; ++r) {
    const unsigned int* gp = (const unsigned int*)(wt + (size_t)(r * 256 + tid) * 8);
    unsigned short* lp = dst + (size_t)(r * 256 + w * 64) * 8;
    __builtin_amdgcn_global_load_lds(
        (const __attribute__((address_space(1))) unsigned int*)gp,
        (__attribute__((address_space(3))) unsigned int*)lp, 16, 0, 0);
  }
}

__global__ __launch_bounds__(256, 2) void adaptive_attn_kernel(
    const float* __restrict__ qg, const unsigned short* __restrict__ ws,
    const float* __restrict__ alphap, float* __restrict__ out) {
  __shared__ unsigned short sBuf[2][TILE_USH];   // 64 KB double buffer only
  // -> 2 blocks/CU on 160KB LDS (8 waves/CU, 2/SIMD)

  const int b    = blockIdx.x;                   // 512 blocks
  const int head = (b & 7) * 4 + ((b >> 3) & 3); // XCD L2 locality swizzle
  const int qt   = b >> 5;                       // 0..15

  const int tid  = threadIdx.x;
  const int w    = tid >> 6;
  const int lane = tid & 63;
  const int g    = lane >> 4;
  const int qi   = lane & 15;

  const float lscale = alphap[0] * 1.44269504088896f;  // alpha * log2(e)

  // Q fragments (B-operand layout) for both query halves, fp16(lscale*Q).
  f16x8 qf[2][4];
#pragma unroll
  for (int h = 0; h < 2; ++h) {
    const int qrow = qt * BQ + w * 32 + h * 16 + qi;
    const float* qp = qg + (size_t)head * S_LEN * HD + (size_t)qrow * HD;
#pragma unroll
    for (int c = 0; c < 4; ++c) {
      float4 a  = *(const float4*)(qp + c * 32 + g * 8);
      float4 bb = *(const float4*)(qp + c * 32 + g * 8 + 4);
      float xs[8] = {a.x, a.y, a.z, a.w, bb.x, bb.y, bb.z, bb.w};
      union { f16x8 v; _Float16 s[8]; } hh;
#pragma unroll
      for (int j = 0; j < 8; ++j) hh.s[j] = (_Float16)(xs[j] * lscale);
      qf[h][c] = hh.v;
    }
  }

  f32x4 o[2][8];
#pragma unroll
  for (int h = 0; h < 2; ++h)
#pragma unroll
    for (int dt = 0; dt < 8; ++dt) o[h][dt] = (f32x4){0.f, 0.f, 0.f, 0.f};
  float lrun[2] = {0.f, 0.f};

  const unsigned short* wsh = ws + (size_t)head * NT * TILE_USH;

  // Prologue: stage tile 0 into buffer 0.
  stage_tile(wsh, &sBuf[0][0], tid, w);
  __syncthreads();

  for (int kt = 0; kt < NT; ++kt) {
    const unsigned short* sK  = &sBuf[kt & 1][0];
    const unsigned short* sVt = sK + 8192;

    // Prefetch next tile; its vmcnt drain hides behind compute.
    if (kt + 1 < NT)
      stage_tile(wsh + (size_t)(kt + 1) * TILE_USH, &sBuf[(kt + 1) & 1][0], tid, w);

    // S^T (64 keys x 32 queries): each K fragment read feeds 2 MFMAs
    // (2 query halves). key&7 == qi&7 since key = mt*16+qi.
    // After QK^T, lane (g,qi) holds S[key=mt*16+g*4+r][query=qi] in
    // st[h][mt][r].
    f32x4 st[2][4];
#pragma unroll
    for (int mt = 0; mt < 4; ++mt) {
      f32x4 a0 = (f32x4){0.f, 0.f, 0.f, 0.f};
      f32x4 a1 = (f32x4){0.f, 0.f, 0.f, 0.f};
#pragma unroll
      for (int c = 0; c < 4; ++c) {
        int ch   = c * 4 + g;
        int slot = (ch & 8) | ((ch & 7) ^ (qi & 7));
        f16x8 ah = *(const f16x8*)&sK[(mt * 16 + qi) * 128 + slot * 8];
        a0 = __builtin_amdgcn_mfma_f32_16x16x32_f16(ah, qf[0][c], a0, 0, 0, 0);
        a1 = __builtin_amdgcn_mfma_f32_16x16x32_f16(ah, qf[1][c], a1, 0, 0, 0);
      }
      st[0][mt] = a0; st[1][mt] = a1;
    }

    // Unnormalized softmax p = exp2(st), then P^T -> A-fragment entirely in
    // registers. pk[mt][u] = {bf16(p[2u]),bf16(p[2u+1])}. For PV, lane (g,qi)
    // needs P[query=qi][keys (c*4+g)*8 + j]: j<4 from lane 16*(2(g&1))+qi,
    // j>=4 from lane 16*(2(g&1)+1)+qi, register set mt = c*2+(g>>1).
    // With A=pk[c*2][u] rows {a0,a1,a2,a3}, B=pk[c*2+1][u]: the two A-words
    // are W0={a0,a2,b0,b2} (even-g sources) and W2={a1,a3,b1,b3} (odd-g):
    // swap32 gives {a0,a1,b0,b1},{a2,a3,b2,b3}; swap16 finishes the shuffle.
    bf16x8 pf[2][2];
#pragma unroll
    for (int h = 0; h < 2; ++h) {
      unsigned pk[4][2];
#pragma unroll
      for (int mt = 0; mt < 4; ++mt) {
        float p0 = fast_exp2(st[h][mt][0]);
        float p1 = fast_exp2(st[h][mt][1]);
        float p2 = fast_exp2(st[h][mt][2]);
        float p3 = fast_exp2(st[h][mt][3]);
        lrun[h] += (p0 + p1) + (p2 + p3);
        pk[mt][0] = cvt_pk_bf16(p0, p1);
        pk[mt][1] = cvt_pk_bf16(p2, p3);
      }
#pragma unroll
      for (int c = 0; c < 2; ++c) {
        uint4v wv;
#pragma unroll
        for (int u = 0; u < 2; ++u) {
          unsigned x = pk[c * 2][u];
          unsigned y = pk[c * 2 + 1][u];
          swap32(x, y);
          swap16(x, y);
          wv[u]     = x;   // word u   : src even g_s, r = 2u, 2u+1
          wv[2 + u] = y;   // word 2+u : src odd  g_s
        }
        pf[h][c] = __builtin_bit_cast(bf16x8, wv);
      }
    }

    // PV: each V fragment read feeds 2 MFMAs (both query halves).
#pragma unroll
    for (int dt = 0; dt < 8; ++dt) {
      f32x4 a0 = o[0][dt];
      f32x4 a1 = o[1][dt];
#pragma unroll
      for (int c = 0; c < 2; ++c) {
        int slot = (c * 4 + g) ^ (qi & 7);   // dim&7 == qi&7
        bf16x8 vf = *(const bf16x8*)&sVt[(dt * 16 + qi) * 64 + slot * 8];
        a0 = __builtin_amdgcn_mfma_f32_16x16x32_bf16(pf[0][c], vf, a0, 0, 0, 0);
        a1 = __builtin_amdgcn_mfma_f32_16x16x32_bf16(pf[1][c], vf, a1, 0, 0, 0);
      }
      o[0][dt] = a0; o[1][dt] = a1;
    }

    // One barrier per iteration: (a) all reads of buf[kt&1] done before
    // iteration kt+1 prefetches kt+2 into it; (b) drains the kt+1 DMA.
    __syncthreads();
  }

  // Epilogue: reduce l across quads, divide, store fp32.
  float* oph = out + (size_t)head * S_LEN * HD + (size_t)(qt * BQ + w * 32) * HD;
#pragma unroll
  for (int h = 0; h < 2; ++h) {
    float ltot = lrun[h];
    ltot += __shfl_xor(ltot, 16, 64);
    ltot += __shfl_xor(ltot, 32, 64);  // lanes with same qi hold l(query qi)
    float inv[4];
#pragma unroll
    for (int r = 0; r < 4; ++r) {
      float lr = __shfl(ltot, g * 4 + r, 64);
      inv[r] = 1.0f / lr;
    }
    float* op = oph + (size_t)(h * 16) * HD;
#pragma unroll
    for (int dt = 0; dt < 8; ++dt) {
#pragma unroll
      for (int r = 0; r < 4; ++r) {
        op[(size_t)(g * 4 + r) * HD + dt * 16 + qi] = o[h][dt][r] * inv[r];
      }
    }
  }
}

extern "C" void kernel_launch(void* const* d_in, const int* in_sizes, int n_in,
                              void* d_out, int out_size, void* d_ws, size_t ws_size,
                              hipStream_t stream) {
  const float* q     = (const float*)d_in[0];
  const float* k     = (const float*)d_in[1];
  const float* v     = (const float*)d_in[2];
  const float* alpha = (const float*)d_in[3];
  float* out = (float*)d_out;
  unsigned short* ws = (unsigned short*)d_ws;   // needs 32 MB

  hipLaunchKernelGGL(attn_prepass_kernel, dim3(1024), dim3(256), 0, stream,
                     k, v, ws);
  hipLaunchKernelGGL(adaptive_attn_kernel, dim3(512), dim3(256), 0, stream,
                     q, ws, alpha, out);
}